// Round 4
// baseline (179.141 us; speedup 1.0000x reference)
//
#include <hip/hip_runtime.h>

// SpatialTransformer: per-batch 3x3 homography warp + bilinear sample of
// image channel 0. image: (B,128,128,3) f32, H: (B,3,3) f32,
// out: (B,128,128,1) f32. B = 2048.
//
// R4: coordinate math restored BIT-IDENTICAL to R1/np-reference (the output
// is discontinuous at clamp boundaries x,y in {0,127}; any perturbation of
// x/y -- rcp, fma reassociation, incremental stepping -- flips boundary
// pixels by O(1)). Structural opts kept: 4 px/thread, dwordx4 tap loads
// (x0 & x1 ch0 at +0B/+12B of one 16B span), nontemporal float4 store.

#define IMG_H 128
#define IMG_W 128

typedef float f32x4 __attribute__((ext_vector_type(4)));
typedef f32x4 f32x4_u __attribute__((aligned(4)));   // 4B-aligned 16B load

__global__ __launch_bounds__(256) void st_warp_kernel(
    const float* __restrict__ img,   // B*128*128*3
    const float* __restrict__ Hm,    // B*9
    float* __restrict__ out)         // B*128*128
{
    // 16 blocks of 256 threads per image; 4 consecutive pixels per thread.
    const int b  = blockIdx.x >> 4;
    const int n0 = ((blockIdx.x & 15) << 10) | (threadIdx.x << 2); // pixel idx
    const int i  = n0 >> 7;    // output row (same for all 4 pixels)
    const int j0 = n0 & 127;   // first output col

    const float* Hb = Hm + b * 9;   // uniform -> scalar loads
    const float h00 = Hb[0], h01 = Hb[1], h02 = Hb[2];
    const float h10 = Hb[3], h11 = Hb[4], h12 = Hb[5];
    const float h20 = Hb[6], h21 = Hb[7], h22 = Hb[8];

    const float step = 2.0f / 127.0f;
    const float yt = -1.0f + step * (float)i;

    const float* imb = img + (size_t)b * (IMG_H * IMG_W * 3);

    float xv[4], yv[4];
    int   x0a[4], x1a[4], y0a[4], y1a[4], xla[4];
    f32x4 r0[4], r1[4];

    // Phase 1: coordinates (bit-identical to reference) + issue all 8 loads
    #pragma unroll
    for (int k = 0; k < 4; ++k) {
        const float xt = -1.0f + step * (float)(j0 + k);
        const float Tx = h00 * xt + h01 * yt + h02;
        const float Ty = h10 * xt + h11 * yt + h12;
        const float Tz = h20 * xt + h21 * yt + h22;
        const float xs = Tx / Tz;          // exact IEEE divide (matches np)
        const float ys = Ty / Tz;
        const float x = (xs + 1.0f) * 64.0f;   // (xs+1)*(W/2), same op order
        const float y = (ys + 1.0f) * 64.0f;
        xv[k] = x; yv[k] = y;
        int x0 = (int)fmaxf(fminf(floorf(x), 2.0e9f), -2.0e9f);
        int y0 = (int)fmaxf(fminf(floorf(y), 2.0e9f), -2.0e9f);
        int x1 = x0 + 1, y1 = y0 + 1;
        x0 = min(max(x0, 0), IMG_W - 1);
        x1 = min(max(x1, 0), IMG_W - 1);
        y0 = min(max(y0, 0), IMG_H - 1);
        y1 = min(max(y1, 0), IMG_H - 1);
        const int xl = min(x0, IMG_W - 2);   // span [xl, xl+1] covers x0 and x1
        x0a[k] = x0; x1a[k] = x1; y0a[k] = y0; y1a[k] = y1; xla[k] = xl;
        r0[k] = *reinterpret_cast<const f32x4_u*>(imb + (y0 * IMG_W + xl) * 3);
        r1[k] = *reinterpret_cast<const f32x4_u*>(imb + (y1 * IMG_W + xl) * 3);
    }

    // Phase 2: bilinear blend (weights from CLIPPED indices = ref semantics)
    f32x4 res;
    #pragma unroll
    for (int k = 0; k < 4; ++k) {
        const float x = xv[k], y = yv[k];
        const int xl = xla[k];
        // element 0 = pixel xl ch0, element 3 (+12B) = pixel xl+1 ch0
        const float Ia = (x0a[k] > xl) ? r0[k].w : r0[k].x;
        const float Ic = (x1a[k] > xl) ? r0[k].w : r0[k].x;
        const float Ib = (x0a[k] > xl) ? r1[k].w : r1[k].x;
        const float Id = (x1a[k] > xl) ? r1[k].w : r1[k].x;
        const float x0f = (float)x0a[k], x1f = (float)x1a[k];
        const float y0f = (float)y0a[k], y1f = (float)y1a[k];
        const float wa = (x1f - x) * (y1f - y);
        const float wb = (x1f - x) * (y - y0f);
        const float wc = (x - x0f) * (y1f - y);
        const float wd = (x - x0f) * (y - y0f);
        res[k] = wa * Ia + wb * Ib + wc * Ic + wd * Id;
    }

    // Streaming output: nontemporal so it doesn't evict cached image lines.
    __builtin_nontemporal_store(res,
        reinterpret_cast<f32x4*>(out + (size_t)b * (IMG_H * IMG_W) + n0));
}

extern "C" void kernel_launch(void* const* d_in, const int* in_sizes, int n_in,
                              void* d_out, int out_size, void* d_ws, size_t ws_size,
                              hipStream_t stream) {
    const float* img = (const float*)d_in[0];   // (2048,128,128,3) f32
    const float* Hm  = (const float*)d_in[1];   // (2048,3,3) f32
    float* out = (float*)d_out;                 // (2048,128,128,1) f32

    const int B = in_sizes[1] / 9;              // 2048
    const int blocks = B * 16;                  // 16 blocks/batch, 256 thr, 4 px/thr
    st_warp_kernel<<<blocks, 256, 0, stream>>>(img, Hm, out);
}

// Round 5
// 126.021 us; speedup vs baseline: 1.4215x; 1.4215x over previous
//
#include <hip/hip_runtime.h>

// SpatialTransformer: per-batch 3x3 homography warp + bilinear sample of
// image channel 0. image: (B,128,128,3) f32, H: (B,3,3) f32,
// out: (B,128,128,1) f32. B = 2048.
//
// R5: R1's bit-identical coordinate math (output is discontinuous at clamp
// boundaries -> must match np exactly), 2 px/thread with scalar 4B tap
// loads (8 loads in flight, ~2x MLP of R1) while staying under the 64-VGPR
// occupancy cliff (R4's arrays pushed past it -> 4 waves/SIMD -> 179us).
// Nontemporal float2 store keeps the output stream out of L2/L3.

#define IMG_H 128
#define IMG_W 128

typedef float f32x2 __attribute__((ext_vector_type(2)));

__global__ __launch_bounds__(256) void st_warp_kernel(
    const float* __restrict__ img,   // B*128*128*3
    const float* __restrict__ Hm,    // B*9
    float* __restrict__ out)         // B*128*128
{
    // 32 blocks of 256 threads per image; 2 consecutive pixels per thread.
    const int b  = blockIdx.x >> 5;
    const int n0 = ((blockIdx.x & 31) << 9) | (threadIdx.x << 1); // pixel idx
    const int i  = n0 >> 7;    // output row (same for both pixels)
    const int j0 = n0 & 127;   // first output col (even, j0+1 <= 127)

    const float* Hb = Hm + b * 9;   // uniform -> scalar loads
    const float h00 = Hb[0], h01 = Hb[1], h02 = Hb[2];
    const float h10 = Hb[3], h11 = Hb[4], h12 = Hb[5];
    const float h20 = Hb[6], h21 = Hb[7], h22 = Hb[8];

    const float step = 2.0f / 127.0f;
    const float yt = -1.0f + step * (float)i;
    const float* imb = img + (size_t)b * (IMG_H * IMG_W * 3);

    // ---- pixel A coordinates (bit-identical to reference) ----
    const float xtA = -1.0f + step * (float)j0;
    const float TxA = h00 * xtA + h01 * yt + h02;
    const float TyA = h10 * xtA + h11 * yt + h12;
    const float TzA = h20 * xtA + h21 * yt + h22;
    const float xA = (TxA / TzA + 1.0f) * 64.0f;
    const float yA = (TyA / TzA + 1.0f) * 64.0f;

    // ---- pixel B coordinates ----
    const float xtB = -1.0f + step * (float)(j0 + 1);
    const float TxB = h00 * xtB + h01 * yt + h02;
    const float TyB = h10 * xtB + h11 * yt + h12;
    const float TzB = h20 * xtB + h21 * yt + h22;
    const float xB = (TxB / TzB + 1.0f) * 64.0f;
    const float yB = (TyB / TzB + 1.0f) * 64.0f;

    // ---- indices ----
    int x0A = (int)fmaxf(fminf(floorf(xA), 2.0e9f), -2.0e9f);
    int y0A = (int)fmaxf(fminf(floorf(yA), 2.0e9f), -2.0e9f);
    int x1A = x0A + 1, y1A = y0A + 1;
    x0A = min(max(x0A, 0), IMG_W - 1); x1A = min(max(x1A, 0), IMG_W - 1);
    y0A = min(max(y0A, 0), IMG_H - 1); y1A = min(max(y1A, 0), IMG_H - 1);

    int x0B = (int)fmaxf(fminf(floorf(xB), 2.0e9f), -2.0e9f);
    int y0B = (int)fmaxf(fminf(floorf(yB), 2.0e9f), -2.0e9f);
    int x1B = x0B + 1, y1B = y0B + 1;
    x0B = min(max(x0B, 0), IMG_W - 1); x1B = min(max(x1B, 0), IMG_W - 1);
    y0B = min(max(y0B, 0), IMG_H - 1); y1B = min(max(y1B, 0), IMG_H - 1);

    // ---- issue all 8 scalar tap loads (independent -> in flight together) ----
    const float IaA = imb[(y0A * IMG_W + x0A) * 3];
    const float IbA = imb[(y1A * IMG_W + x0A) * 3];
    const float IcA = imb[(y0A * IMG_W + x1A) * 3];
    const float IdA = imb[(y1A * IMG_W + x1A) * 3];
    const float IaB = imb[(y0B * IMG_W + x0B) * 3];
    const float IbB = imb[(y1B * IMG_W + x0B) * 3];
    const float IcB = imb[(y0B * IMG_W + x1B) * 3];
    const float IdB = imb[(y1B * IMG_W + x1B) * 3];

    // ---- blend (weights from CLIPPED indices = ref semantics) ----
    f32x2 res;
    {
        const float x0f = (float)x0A, x1f = (float)x1A;
        const float y0f = (float)y0A, y1f = (float)y1A;
        const float wa = (x1f - xA) * (y1f - yA);
        const float wb = (x1f - xA) * (yA - y0f);
        const float wc = (xA - x0f) * (y1f - yA);
        const float wd = (xA - x0f) * (yA - y0f);
        res.x = wa * IaA + wb * IbA + wc * IcA + wd * IdA;
    }
    {
        const float x0f = (float)x0B, x1f = (float)x1B;
        const float y0f = (float)y0B, y1f = (float)y1B;
        const float wa = (x1f - xB) * (y1f - yB);
        const float wb = (x1f - xB) * (yB - y0f);
        const float wc = (xB - x0f) * (y1f - yB);
        const float wd = (xB - x0f) * (yB - y0f);
        res.y = wa * IaB + wb * IbB + wc * IcB + wd * IdB;
    }

    __builtin_nontemporal_store(res,
        reinterpret_cast<f32x2*>(out + (size_t)b * (IMG_H * IMG_W) + n0));
}

extern "C" void kernel_launch(void* const* d_in, const int* in_sizes, int n_in,
                              void* d_out, int out_size, void* d_ws, size_t ws_size,
                              hipStream_t stream) {
    const float* img = (const float*)d_in[0];   // (2048,128,128,3) f32
    const float* Hm  = (const float*)d_in[1];   // (2048,3,3) f32
    float* out = (float*)d_out;                 // (2048,128,128,1) f32

    const int B = in_sizes[1] / 9;              // 2048
    const int blocks = B * 32;                  // 32 blocks/batch, 256 thr, 2 px/thr
    st_warp_kernel<<<blocks, 256, 0, stream>>>(img, Hm, out);
}

// Round 6
// 114.037 us; speedup vs baseline: 1.5709x; 1.1051x over previous
//
#include <hip/hip_runtime.h>

// SpatialTransformer: per-batch 3x3 homography warp + bilinear sample of
// image channel 0. image: (B,128,128,3) f32, H: (B,3,3) f32,
// out: (B,128,128,1) f32. B = 2048.
//
// R6 = R5 (bit-identical coord math, 2 px/thread, NT store) plus:
//  - dwordx4 tap loads: ch0 of px x0 and x1 live at +0B/+12B of one 16B
//    span -> 4 gathers/thread instead of 8 (halves L1 transactions).
//    Value-identical select picks elem0/elem3 per clamped index.
//  - XCD swizzle: all 32 blocks of one image map to the same XCD (dispatch
//    round-robins blockIdx%8 across XCDs), so the 192KB image stays in one
//    L2 -> gathers hit L2 instead of L3/HBM.

#define IMG_H 128
#define IMG_W 128

typedef float f32x2 __attribute__((ext_vector_type(2)));
typedef float f32x4 __attribute__((ext_vector_type(4)));
typedef f32x4 f32x4_u __attribute__((aligned(4)));   // 4B-aligned 16B load

__global__ __launch_bounds__(256) void st_warp_kernel(
    const float* __restrict__ img,   // B*128*128*3
    const float* __restrict__ Hm,    // B*9
    float* __restrict__ out)         // B*128*128
{
    // Decode XCD-swizzled block id: image b occupies blocks with
    // blockIdx % 8 == b % 8  (one XCD per image).
    const int s = blockIdx.x;
    const int x = s & 7;
    const int r = s >> 3;
    const int j = r & 31;                  // chunk within image, 0..31
    const int b = ((r >> 5) << 3) | x;     // image index

    const int n0 = (j << 9) | (threadIdx.x << 1);   // pixel idx in image
    const int i  = n0 >> 7;    // output row (same for both pixels)
    const int j0 = n0 & 127;   // first output col (even)

    const float* Hb = Hm + b * 9;   // uniform -> scalar loads
    const float h00 = Hb[0], h01 = Hb[1], h02 = Hb[2];
    const float h10 = Hb[3], h11 = Hb[4], h12 = Hb[5];
    const float h20 = Hb[6], h21 = Hb[7], h22 = Hb[8];

    const float step = 2.0f / 127.0f;
    const float yt = -1.0f + step * (float)i;
    const float* imb = img + (size_t)b * (IMG_H * IMG_W * 3);

    // ---- pixel A coordinates (bit-identical to reference) ----
    const float xtA = -1.0f + step * (float)j0;
    const float TxA = h00 * xtA + h01 * yt + h02;
    const float TyA = h10 * xtA + h11 * yt + h12;
    const float TzA = h20 * xtA + h21 * yt + h22;
    const float xA = (TxA / TzA + 1.0f) * 64.0f;
    const float yA = (TyA / TzA + 1.0f) * 64.0f;

    // ---- pixel B coordinates ----
    const float xtB = -1.0f + step * (float)(j0 + 1);
    const float TxB = h00 * xtB + h01 * yt + h02;
    const float TyB = h10 * xtB + h11 * yt + h12;
    const float TzB = h20 * xtB + h21 * yt + h22;
    const float xB = (TxB / TzB + 1.0f) * 64.0f;
    const float yB = (TyB / TzB + 1.0f) * 64.0f;

    // ---- indices ----
    int x0A = (int)fmaxf(fminf(floorf(xA), 2.0e9f), -2.0e9f);
    int y0A = (int)fmaxf(fminf(floorf(yA), 2.0e9f), -2.0e9f);
    int x1A = x0A + 1, y1A = y0A + 1;
    x0A = min(max(x0A, 0), IMG_W - 1); x1A = min(max(x1A, 0), IMG_W - 1);
    y0A = min(max(y0A, 0), IMG_H - 1); y1A = min(max(y1A, 0), IMG_H - 1);
    const int xlA = min(x0A, IMG_W - 2);

    int x0B = (int)fmaxf(fminf(floorf(xB), 2.0e9f), -2.0e9f);
    int y0B = (int)fmaxf(fminf(floorf(yB), 2.0e9f), -2.0e9f);
    int x1B = x0B + 1, y1B = y0B + 1;
    x0B = min(max(x0B, 0), IMG_W - 1); x1B = min(max(x1B, 0), IMG_W - 1);
    y0B = min(max(y0B, 0), IMG_H - 1); y1B = min(max(y1B, 0), IMG_H - 1);
    const int xlB = min(x0B, IMG_W - 2);

    // ---- 4 dwordx4 gathers (each covers ch0 of px xl and xl+1) ----
    const f32x4 rA0 = *reinterpret_cast<const f32x4_u*>(imb + (y0A * IMG_W + xlA) * 3);
    const f32x4 rA1 = *reinterpret_cast<const f32x4_u*>(imb + (y1A * IMG_W + xlA) * 3);
    const f32x4 rB0 = *reinterpret_cast<const f32x4_u*>(imb + (y0B * IMG_W + xlB) * 3);
    const f32x4 rB1 = *reinterpret_cast<const f32x4_u*>(imb + (y1B * IMG_W + xlB) * 3);

    // ---- blend (weights from CLIPPED indices = ref semantics) ----
    f32x2 res;
    {
        const float Ia = (x0A > xlA) ? rA0.w : rA0.x;
        const float Ic = (x1A > xlA) ? rA0.w : rA0.x;
        const float Ib = (x0A > xlA) ? rA1.w : rA1.x;
        const float Id = (x1A > xlA) ? rA1.w : rA1.x;
        const float x0f = (float)x0A, x1f = (float)x1A;
        const float y0f = (float)y0A, y1f = (float)y1A;
        const float wa = (x1f - xA) * (y1f - yA);
        const float wb = (x1f - xA) * (yA - y0f);
        const float wc = (xA - x0f) * (y1f - yA);
        const float wd = (xA - x0f) * (yA - y0f);
        res.x = wa * Ia + wb * Ib + wc * Ic + wd * Id;
    }
    {
        const float Ia = (x0B > xlB) ? rB0.w : rB0.x;
        const float Ic = (x1B > xlB) ? rB0.w : rB0.x;
        const float Ib = (x0B > xlB) ? rB1.w : rB1.x;
        const float Id = (x1B > xlB) ? rB1.w : rB1.x;
        const float x0f = (float)x0B, x1f = (float)x1B;
        const float y0f = (float)y0B, y1f = (float)y1B;
        const float wa = (x1f - xB) * (y1f - yB);
        const float wb = (x1f - xB) * (yB - y0f);
        const float wc = (xB - x0f) * (y1f - yB);
        const float wd = (xB - x0f) * (yB - y0f);
        res.y = wa * Ia + wb * Ib + wc * Ic + wd * Id;
    }

    __builtin_nontemporal_store(res,
        reinterpret_cast<f32x2*>(out + (size_t)b * (IMG_H * IMG_W) + n0));
}

extern "C" void kernel_launch(void* const* d_in, const int* in_sizes, int n_in,
                              void* d_out, int out_size, void* d_ws, size_t ws_size,
                              hipStream_t stream) {
    const float* img = (const float*)d_in[0];   // (2048,128,128,3) f32
    const float* Hm  = (const float*)d_in[1];   // (2048,3,3) f32
    float* out = (float*)d_out;                 // (2048,128,128,1) f32

    const int B = in_sizes[1] / 9;              // 2048
    const int blocks = B * 32;                  // 32 blocks/image, 2 px/thr
    st_warp_kernel<<<blocks, 256, 0, stream>>>(img, Hm, out);
}

// Round 7
// 113.366 us; speedup vs baseline: 1.5802x; 1.0059x over previous
//
#include <hip/hip_runtime.h>

// SpatialTransformer: per-batch 3x3 homography warp + bilinear sample of
// image channel 0. image: (B,128,128,3) f32, H: (B,3,3) f32,
// out: (B,128,128,1) f32. B = 2048.
//
// R7: one block per image. Stage the ch0 plane (64KB) into LDS with fully
// coalesced dwordx4 loads (12 floats -> 4 ch0 values at +0,+3,+6,+9 ->
// one ds_write_b128), then bilinear-gather from LDS. This removes the
// vector-path L1 line-gather bottleneck (each image HBM line now fetched
// exactly once, fully consumed). Coordinate math bit-identical to R1/np
// (output discontinuous at clamp boundaries; R3 proved perturbation fails).

#define IMG_H 128
#define IMG_W 128
#define NPIX  (IMG_H * IMG_W)    // 16384
#define NFLT  (NPIX * 3)         // 49152
#define TPB   1024

typedef float f32x4 __attribute__((ext_vector_type(4)));

__global__ __launch_bounds__(TPB, 8) void st_warp_kernel(
    const float* __restrict__ img,   // B*128*128*3
    const float* __restrict__ Hm,    // B*9
    float* __restrict__ out)         // B*128*128
{
    __shared__ float sh[NPIX];       // ch0 plane, 65536 B

    const int b = blockIdx.x;
    const int t = threadIdx.x;
    const float* imb = img + (size_t)b * NFLT;

    // H loads issued before staging so the s_loads overlap the streaming.
    const float* Hb = Hm + b * 9;    // uniform across block -> scalar loads
    const float h00 = Hb[0], h01 = Hb[1], h02 = Hb[2];
    const float h10 = Hb[3], h11 = Hb[4], h12 = Hb[5];
    const float h20 = Hb[6], h21 = Hb[7], h22 = Hb[8];

    // ---- stage: 4096 chunks of 12 floats each -> 4 contiguous LDS floats
    #pragma unroll
    for (int p = 0; p < 4; ++p) {
        const int c = t + p * TPB;               // chunk id, < 4096
        const float* src = imb + c * 12;         // 48B-aligned
        const f32x4 v0 = *reinterpret_cast<const f32x4*>(src);
        const f32x4 v1 = *reinterpret_cast<const f32x4*>(src + 4);
        const f32x4 v2 = *reinterpret_cast<const f32x4*>(src + 8);
        f32x4 w;
        w.x = v0.x;   // float f0+0  (ch0 of px 4c+0)
        w.y = v0.w;   // float f0+3  (ch0 of px 4c+1)
        w.z = v1.z;   // float f0+6  (ch0 of px 4c+2)
        w.w = v2.y;   // float f0+9  (ch0 of px 4c+3)
        *reinterpret_cast<f32x4*>(&sh[c * 4]) = w;   // 16B-aligned
    }
    __syncthreads();

    const float step = 2.0f / 127.0f;
    float* outb = out + (size_t)b * NPIX;

    #pragma unroll 1
    for (int k = 0; k < NPIX / TPB; ++k) {   // 16 pixels/thread
        const int n = t + k * TPB;
        const int i = n >> 7;     // row: wave's 64 lanes share one row
        const int j = n & 127;    // col: consecutive lanes -> consecutive cols

        // ---- coordinates (bit-identical to reference) ----
        const float yt = -1.0f + step * (float)i;
        const float xt = -1.0f + step * (float)j;
        const float Tx = h00 * xt + h01 * yt + h02;
        const float Ty = h10 * xt + h11 * yt + h12;
        const float Tz = h20 * xt + h21 * yt + h22;
        const float x = (Tx / Tz + 1.0f) * 64.0f;   // exact IEEE divide
        const float y = (Ty / Tz + 1.0f) * 64.0f;

        int x0 = (int)fmaxf(fminf(floorf(x), 2.0e9f), -2.0e9f);
        int y0 = (int)fmaxf(fminf(floorf(y), 2.0e9f), -2.0e9f);
        int x1 = x0 + 1, y1 = y0 + 1;
        x0 = min(max(x0, 0), IMG_W - 1);
        x1 = min(max(x1, 0), IMG_W - 1);
        y0 = min(max(y0, 0), IMG_H - 1);
        y1 = min(max(y1, 0), IMG_H - 1);
        const int xl = min(x0, IMG_W - 2);   // [xl, xl+1] covers x0 and x1

        // ---- LDS gather: 2 row-pairs, consecutive banks across lanes ----
        const float lo0 = sh[(y0 << 7) + xl];
        const float hi0 = sh[(y0 << 7) + xl + 1];
        const float lo1 = sh[(y1 << 7) + xl];
        const float hi1 = sh[(y1 << 7) + xl + 1];
        const float Ia = (x0 > xl) ? hi0 : lo0;
        const float Ic = (x1 > xl) ? hi0 : lo0;
        const float Ib = (x0 > xl) ? hi1 : lo1;
        const float Id = (x1 > xl) ? hi1 : lo1;

        // ---- blend (weights from CLIPPED indices = ref semantics) ----
        const float x0f = (float)x0, x1f = (float)x1;
        const float y0f = (float)y0, y1f = (float)y1;
        const float wa = (x1f - x) * (y1f - y);
        const float wb = (x1f - x) * (y - y0f);
        const float wc = (x - x0f) * (y1f - y);
        const float wd = (x - x0f) * (y - y0f);

        __builtin_nontemporal_store(wa * Ia + wb * Ib + wc * Ic + wd * Id,
                                    outb + n);
    }
}

extern "C" void kernel_launch(void* const* d_in, const int* in_sizes, int n_in,
                              void* d_out, int out_size, void* d_ws, size_t ws_size,
                              hipStream_t stream) {
    const float* img = (const float*)d_in[0];   // (2048,128,128,3) f32
    const float* Hm  = (const float*)d_in[1];   // (2048,3,3) f32
    float* out = (float*)d_out;                 // (2048,128,128,1) f32

    const int B = in_sizes[1] / 9;              // 2048 blocks, 1 image each
    st_warp_kernel<<<B, TPB, 0, stream>>>(img, Hm, out);
}